// Round 16
// baseline (3845.065 us; speedup 1.0000x reference)
//
#include <hip/hip_runtime.h>
#include <hip/hip_fp16.h>
#include <math.h>

// Problem constants
#define HH 320
#define WW 320
#define NP (HH*WW)        // 102400
#define CC 32
#define DD 32

#define H2 160
#define W2 160
#define N2 (H2*W2)        // 25600
#define H4 80
#define W4 80
#define N4 (H4*W4)        // 6400
#define H8 40
#define W8 40
#define N8 (H8*W8)        // 1600

#define HALO 18
#define NHALO (HALO*HALO) // 324

// ring strides (floats)
#define C1SZ (8*NP)       // 819200
#define C2SZ (16*N2)      // 409600
#define C3SZ (32*N4)      // 204800
#define C4SZ (64*N8)      // 102400

// stageA [16][NHALO] half2 = 20736 B (s1 [8][NHALO] f32 aliased);
// stageU needs 5344 f32 = 21376 B -> governs allocation.
// 6 blocks/CU x 21376 B = 128 KB < 160 KB LDS: fits.
#define SMEM_FLOATS 5344

// ---------------- workspace layout (float offsets) ----------------
#define OFF_REL   0                        // 24 used, pad 64
#define OFF_C1R   64                       // ring of 5
#define OFF_C2R   (OFF_C1R + 5*C1SZ)       // ring of 4
#define OFF_C3R   (OFF_C2R + 4*C2SZ)       // ring of 3
#define OFF_C4R   (OFF_C3R + 3*C3SZ)       // ring of 2
#define OFF_ESUM  (OFF_C4R + 2*C4SZ)
#define OFF_DIMG  (OFF_ESUM + NP)
#define OFF_MAXP  (OFF_DIMG + NP)
#define OFF_ACCE  (OFF_MAXP + NP)          // end of zero-init region (~27.4 MiB)
// channel-last fp16 copy of feats: [3 views][NP][32 ch] (+19.7 MiB)
#define OFF_FT    OFF_ACCE
#define OFF_END   (OFF_FT + (3*CC*NP)/2)

// ---------------- prep: rel = proj[v] @ inv(proj[0]), v=1,2 ----------------
__global__ void k_prep(const float* __restrict__ proj, float* __restrict__ rel) {
    if (threadIdx.x != 0 || blockIdx.x != 0) return;
    float a[4][4], inv[4][4];
#pragma unroll
    for (int i = 0; i < 4; i++)
#pragma unroll
        for (int j = 0; j < 4; j++) {
            a[i][j] = proj[i*4 + j];
            inv[i][j] = (i == j) ? 1.0f : 0.0f;
        }
#pragma unroll
    for (int c = 0; c < 4; c++) {
        float s = 1.0f / a[c][c];
#pragma unroll
        for (int j = 0; j < 4; j++) { a[c][j] *= s; inv[c][j] *= s; }
#pragma unroll
        for (int r = 0; r < 4; r++) if (r != c) {
            float f = a[r][c];
#pragma unroll
            for (int j = 0; j < 4; j++) {
                a[r][j] -= f * a[c][j];
                inv[r][j] -= f * inv[c][j];
            }
        }
    }
#pragma unroll
    for (int v = 1; v < 3; v++) {
        const float* P = proj + v*16;
        float rm[3][4];
#pragma unroll
        for (int i = 0; i < 3; i++)
#pragma unroll
            for (int j = 0; j < 4; j++) {
                float s = 0.0f;
#pragma unroll
                for (int k = 0; k < 4; k++) s += P[i*4 + k] * inv[k][j];
                rm[i][j] = s;
            }
        float* o = rel + (v-1)*12;
        o[0]=rm[0][0]; o[1]=rm[0][1]; o[2]=rm[0][2];
        o[3]=rm[1][0]; o[4]=rm[1][1]; o[5]=rm[1][2];
        o[6]=rm[2][0]; o[7]=rm[2][1]; o[8]=rm[2][2];
        o[9]=rm[0][3]; o[10]=rm[1][3]; o[11]=rm[2][3];
    }
}

// ---------------- CHW f32 -> HWC fp16 transpose of all 3 views ------------
__global__ __launch_bounds__(256) void k_transpose(const float* __restrict__ feats,
                                                   __half* __restrict__ featsT) {
    __shared__ float lds[32][65];   // +1 pad
    int g = blockIdx.x;
    int v = g / 1600;
    int p0 = (g - v*1600) * 64;
    const float* src = feats + (size_t)v*CC*NP + p0;
    for (int i = threadIdx.x; i < 32*64; i += 256) {
        int c = i >> 6, pp = i & 63;
        lds[c][pp] = src[(size_t)c*NP + pp];       // coalesced reads
    }
    __syncthreads();
    __half* dst = featsT + ((size_t)v*NP + p0)*32;
    int pp = threadIdx.x >> 2, cq = (threadIdx.x & 3) * 8;
    __half2 h[4];
#pragma unroll
    for (int j = 0; j < 4; j++)
        h[j] = __floats2half2_rn(lds[cq+2*j][pp], lds[cq+2*j+1][pp]);
    *(float4*)(dst + (size_t)pp*32 + cq) = *(float4*)h;   // 16B coalesced store
}

// ---- fp16 8-channel (16 B) helpers ----
__device__ __forceinline__ void set_hline8(const __half* base, float* s) {
    float4 raw = *(const float4*)base;
    const __half2* h2 = (const __half2*)&raw;
#pragma unroll
    for (int j = 0; j < 4; j++) {
        float2 f = __half22float2(h2[j]);
        s[2*j]     = f.x;
        s[2*j + 1] = f.y;
    }
}
__device__ __forceinline__ void acc_hline8(const __half* base, float w, float* t) {
    float4 raw = *(const float4*)base;
    const __half2* h2 = (const __half2*)&raw;
#pragma unroll
    for (int j = 0; j < 4; j++) {
        float2 f = __half22float2(h2[j]);
        t[2*j]     += f.x * w;
        t[2*j + 1] += f.y * w;
    }
}

// XCD band swizzle (round-robin block->XCD).
__device__ __forceinline__ int band_tile(int blk) { return (blk & 7) * 50 + (blk >> 3); } // [0,400)

// ================= stage device functions =================
// Rule-#20 fix: offs[]/wts[] are accessed ONLY with compile-time indices
// (view/tap loops fully unrolled) so they live in VGPRs, not scratch.
// Round-15's rolled v/tp loops dynamically indexed these arrays -> the
// compiler placed them in scratch -> 50+ MB/dispatch of scratch traffic
// (WRITE_SIZE 58 MB) that was misread as register spilling.

// A: warp+variance+conv1, 16x16 tile; blk in [0,400) band-swizzled.
__device__ void stageA(int blk, int d, int useT,
        const float* __restrict__ feats, const __half* __restrict__ featsT,
        const float* __restrict__ rel,
        const float* __restrict__ depthv, const float* __restrict__ c1r,
        const float* __restrict__ W0, const float* __restrict__ Ws1,
        float* smem) {
    __half2* pbuf = (__half2*)smem;       // [16 ch-pairs][NHALO]
    float* fbuf = smem;                   // [8][NHALO] for the s1 phase
    const float* dslice = depthv + (size_t)d * NP;
    const float* s1 = c1r + (size_t)((d+4)%5) * C1SZ;   // c1_{d-1} (zeros for d=0)
    float* c1out = (float*)c1r + (size_t)(d%5) * C1SZ;

    int L = band_tile(blk);
    int bx = L % 20, by = L / 20;
    int ox0 = bx*16, oy0 = by*16;

    const float inv3 = 1.0f / 3.0f;

    int opx = threadIdx.x & 15, opy = threadIdx.x >> 4;
    int obase = opy*HALO + opx;
    int outp = (oy0 + opy)*WW + ox0 + opx;

    // ---- variance pass: <=2 halo pixels / thread, 4 channel-quarters ----
#pragma unroll 1
    for (int s = 0; s < 2; s++) {
        int hp = threadIdx.x + s*256;
        if (hp >= NHALO) break;
        int hy = hp / HALO, hx = hp - hy*HALO;
        int gy = oy0 + hy - 1, gx = ox0 + hx - 1;
        if (gy < 0 || gy >= HH || gx < 0 || gx >= WW) {
            __half2 z = __floats2half2_rn(0.0f, 0.0f);
#pragma unroll 1
            for (int c = 0; c < 16; c++) pbuf[c*NHALO + hp] = z;
            continue;
        }
        int p = gy*WW + gx;
        float depth = dslice[p];
        float fx = (float)gx, fy = (float)gy;

        // tap offsets/weights once per pixel — FULLY UNROLLED (static idx)
        int offs[8]; float wts[8];
#pragma unroll
        for (int v = 0; v < 2; v++) {
            const float* r = rel + v*12;
            float X = (r[0]*fx + r[1]*fy + r[2]) * depth + r[9];
            float Y = (r[3]*fx + r[4]*fy + r[5]) * depth + r[10];
            float Z = (r[6]*fx + r[7]*fy + r[8]) * depth + r[11];
            float iz = 1.0f / Z;
            float px = X * iz, py = Y * iz;
            float x0f = floorf(px), y0f = floorf(py);
            float wx = px - x0f, wy = py - y0f;
            int x0 = (int)x0f, y0 = (int)y0f;
#pragma unroll
            for (int t = 0; t < 4; t++) {
                int xi = x0 + (t & 1), yi = y0 + (t >> 1);
                float wgt = ((t & 1) ? wx : 1.0f - wx) * ((t >> 1) ? wy : 1.0f - wy);
                bool valid = (xi >= 0) && (xi <= WW-1) && (yi >= 0) && (yi <= HH-1);
                int xc = min(max(xi, 0), WW-1);
                int yc = min(max(yi, 0), HH-1);
                offs[v*4 + t] = yc*WW + xc;
                wts[v*4 + t] = valid ? wgt : 0.0f;
            }
        }

#pragma unroll 1
        for (int q = 0; q < 4; q++) {
            int cb = q * 8;
            float sum[8], sq[8], t[8];
            if (useT) {
                set_hline8(featsT + ((size_t)p << 5) + cb, sum);
#pragma unroll
                for (int c = 0; c < 8; c++) sq[c] = sum[c]*sum[c];
                // view 1 — static offs/wts indices
                const __half* f1h = featsT + (size_t)CC*NP;
#pragma unroll
                for (int c = 0; c < 8; c++) t[c] = 0.0f;
                acc_hline8(f1h + ((size_t)offs[0] << 5) + cb, wts[0], t);
                acc_hline8(f1h + ((size_t)offs[1] << 5) + cb, wts[1], t);
                acc_hline8(f1h + ((size_t)offs[2] << 5) + cb, wts[2], t);
                acc_hline8(f1h + ((size_t)offs[3] << 5) + cb, wts[3], t);
#pragma unroll
                for (int c = 0; c < 8; c++) { sum[c] += t[c]; sq[c] += t[c]*t[c]; }
                // view 2 — static offs/wts indices
                const __half* f2h = featsT + (size_t)2*CC*NP;
#pragma unroll
                for (int c = 0; c < 8; c++) t[c] = 0.0f;
                acc_hline8(f2h + ((size_t)offs[4] << 5) + cb, wts[4], t);
                acc_hline8(f2h + ((size_t)offs[5] << 5) + cb, wts[5], t);
                acc_hline8(f2h + ((size_t)offs[6] << 5) + cb, wts[6], t);
                acc_hline8(f2h + ((size_t)offs[7] << 5) + cb, wts[7], t);
#pragma unroll
                for (int c = 0; c < 8; c++) { sum[c] += t[c]; sq[c] += t[c]*t[c]; }
            } else {
                const float* f1 = feats + CC*NP;
                const float* f2 = feats + 2*CC*NP;
#pragma unroll 1
                for (int c = 0; c < 8; c++) {
                    int cg = cb + c;
                    float rv = feats[cg*NP + p];
                    const float* b1 = f1 + cg*NP;
                    float t1 = b1[offs[0]]*wts[0] + b1[offs[1]]*wts[1]
                             + b1[offs[2]]*wts[2] + b1[offs[3]]*wts[3];
                    const float* b2 = f2 + cg*NP;
                    float t2 = b2[offs[4]]*wts[4] + b2[offs[5]]*wts[5]
                             + b2[offs[6]]*wts[6] + b2[offs[7]]*wts[7];
                    sum[c] = rv + t1 + t2;
                    sq[c]  = rv*rv + t1*t1 + t2*t2;
                }
            }
#pragma unroll
            for (int c = 0; c < 4; c++) {
                float m0 = sum[2*c] * inv3,   v0 = sq[2*c] * inv3 - m0*m0;
                float m1 = sum[2*c+1] * inv3, v1 = sq[2*c+1] * inv3 - m1*m1;
                pbuf[(q*4 + c)*NHALO + hp] = __floats2half2_rn(v0, v1);
            }
        }
    }
    __syncthreads();

    float acc[8];
#pragma unroll
    for (int o = 0; o < 8; o++) acc[o] = 0.0f;

#pragma unroll 1
    for (int cp = 0; cp < 16; cp++) {
        float t0[9], t1[9];
#pragma unroll
        for (int ky = 0; ky < 3; ky++)
#pragma unroll
            for (int kx = 0; kx < 3; kx++) {
                __half2 h = pbuf[cp*NHALO + obase + ky*HALO + kx];
                t0[ky*3+kx] = __low2float(h);
                t1[ky*3+kx] = __high2float(h);
            }
#pragma unroll
        for (int o = 0; o < 8; o++) {
            const float* w0 = W0 + (o*32 + 2*cp)*9;
            float a = acc[o];
#pragma unroll
            for (int k = 0; k < 9; k++) a += t0[k] * w0[k];
#pragma unroll
            for (int k = 0; k < 9; k++) a += t1[k] * w0[9 + k];
            acc[o] = a;
        }
    }
    __syncthreads();   // before s1 staging overwrites buf

    // s1 chunk (8 channels, f32 in LDS)
#pragma unroll 1
    for (int hp = threadIdx.x; hp < NHALO; hp += 256) {
        int hy = hp / HALO, hx = hp - hy*HALO;
        int gy = oy0 + hy - 1, gx = ox0 + hx - 1;
        bool v = (gy >= 0) && (gy < HH) && (gx >= 0) && (gx < WW);
        int p = v ? gy*WW + gx : 0;
#pragma unroll
        for (int c = 0; c < 8; c++) fbuf[c*NHALO + hp] = v ? s1[c*NP + p] : 0.0f;
    }
    __syncthreads();
#pragma unroll 1
    for (int ci = 0; ci < 8; ci++) {
        float t[9];
#pragma unroll
        for (int ky = 0; ky < 3; ky++)
#pragma unroll
            for (int kx = 0; kx < 3; kx++) t[ky*3+kx] = fbuf[ci*NHALO + obase + ky*HALO + kx];
#pragma unroll
        for (int o = 0; o < 8; o++) {
            const float* w = Ws1 + (o*8 + ci)*9;
            float a = acc[o];
#pragma unroll
            for (int k = 0; k < 9; k++) a += t[k] * w[k];
            acc[o] = a;
        }
    }
#pragma unroll
    for (int o = 0; o < 8; o++) c1out[o*NP + outp] = fmaxf(acc[o], 0.0f);
}

// B: conv2. blk in [0,200): px_chunk = blk%100, og = blk/100 (2 groups of 8)
__device__ void stageB(int blk, int d,
        const float* __restrict__ c1r, const float* __restrict__ c2r_,
        const float* __restrict__ W1, const float* __restrict__ Ws2) {
    const float* c1 = c1r + (size_t)(d%5) * C1SZ;
    const float* s2 = c2r_ + (size_t)((d+3)%4) * C2SZ;
    float* c2 = (float*)c2r_ + (size_t)(d%4) * C2SZ;
    int p = (blk % 100)*256 + threadIdx.x;
    int og = blk / 100;
    int y = p / W2, x = p - y*W2;
    int offsA[9]; float mskA[9];
#pragma unroll
    for (int k = 0; k < 9; k++) {
        int yy = 2*y + k/3, xx = 2*x + k%3;
        bool v = (yy < HH) && (xx < WW);
        offsA[k] = v ? yy*WW + xx : 0;
        mskA[k] = v ? 1.0f : 0.0f;
    }
    int offsB[9]; float mskB[9];
#pragma unroll
    for (int k = 0; k < 9; k++) {
        int yy = y + k/3 - 1, xx = x + k%3 - 1;
        bool v = (yy >= 0) && (yy < H2) && (xx >= 0) && (xx < W2);
        offsB[k] = v ? yy*W2 + xx : 0;
        mskB[k] = v ? 1.0f : 0.0f;
    }
    float acc[8];
#pragma unroll
    for (int o = 0; o < 8; o++) acc[o] = 0.0f;
#pragma unroll 1
    for (int ci = 0; ci < 8; ci++) {
        const float* b = c1 + ci*NP;
        float t[9];
#pragma unroll
        for (int k = 0; k < 9; k++) t[k] = b[offsA[k]] * mskA[k];
#pragma unroll
        for (int o = 0; o < 8; o++) {
            const float* w = W1 + ((og*8 + o)*8 + ci)*9;
            float a = acc[o];
#pragma unroll
            for (int k = 0; k < 9; k++) a += t[k] * w[k];
            acc[o] = a;
        }
    }
#pragma unroll 1
    for (int ci = 0; ci < 16; ci++) {
        const float* b = s2 + ci*N2;
        float t[9];
#pragma unroll
        for (int k = 0; k < 9; k++) t[k] = b[offsB[k]] * mskB[k];
#pragma unroll
        for (int o = 0; o < 8; o++) {
            const float* w = Ws2 + ((og*8 + o)*16 + ci)*9;
            float a = acc[o];
#pragma unroll
            for (int k = 0; k < 9; k++) a += t[k] * w[k];
            acc[o] = a;
        }
    }
#pragma unroll
    for (int o = 0; o < 8; o++) c2[(og*8 + o)*N2 + p] = fmaxf(acc[o], 0.0f);
}

// C: conv3. blk in [0,100): px_chunk = blk%25, og = blk/25 (4 groups of 8)
__device__ void stageC(int blk, int d,
        const float* __restrict__ c2r_, const float* __restrict__ c3r_,
        const float* __restrict__ W2w, const float* __restrict__ Ws3) {
    const float* c2 = c2r_ + (size_t)(d%4) * C2SZ;
    const float* s3 = c3r_ + (size_t)((d+2)%3) * C3SZ;
    float* c3 = (float*)c3r_ + (size_t)(d%3) * C3SZ;
    int p = (blk % 25)*256 + threadIdx.x;
    int og = blk / 25;
    int y = p / W4, x = p - y*W4;
    int offsA[9]; float mskA[9];
#pragma unroll
    for (int k = 0; k < 9; k++) {
        int yy = 2*y + k/3, xx = 2*x + k%3;
        bool v = (yy < H2) && (xx < W2);
        offsA[k] = v ? yy*W2 + xx : 0;
        mskA[k] = v ? 1.0f : 0.0f;
    }
    int offsB[9]; float mskB[9];
#pragma unroll
    for (int k = 0; k < 9; k++) {
        int yy = y + k/3 - 1, xx = x + k%3 - 1;
        bool v = (yy >= 0) && (yy < H4) && (xx >= 0) && (xx < W4);
        offsB[k] = v ? yy*W4 + xx : 0;
        mskB[k] = v ? 1.0f : 0.0f;
    }
    float acc[8];
#pragma unroll
    for (int o = 0; o < 8; o++) acc[o] = 0.0f;
#pragma unroll 1
    for (int ci = 0; ci < 16; ci++) {
        const float* b = c2 + ci*N2;
        float t[9];
#pragma unroll
        for (int k = 0; k < 9; k++) t[k] = b[offsA[k]] * mskA[k];
#pragma unroll
        for (int o = 0; o < 8; o++) {
            const float* w = W2w + ((og*8 + o)*16 + ci)*9;
            float a = acc[o];
#pragma unroll
            for (int k = 0; k < 9; k++) a += t[k] * w[k];
            acc[o] = a;
        }
    }
#pragma unroll 1
    for (int ci = 0; ci < 32; ci++) {
        const float* b = s3 + ci*N4;
        float t[9];
#pragma unroll
        for (int k = 0; k < 9; k++) t[k] = b[offsB[k]] * mskB[k];
#pragma unroll
        for (int o = 0; o < 8; o++) {
            const float* w = Ws3 + ((og*8 + o)*32 + ci)*9;
            float a = acc[o];
#pragma unroll
            for (int k = 0; k < 9; k++) a += t[k] * w[k];
            acc[o] = a;
        }
    }
#pragma unroll
    for (int o = 0; o < 8; o++) c3[(og*8 + o)*N4 + p] = fmaxf(acc[o], 0.0f);
}

// D: conv4. blk in [0,56): px_chunk = blk%7, og = blk/7 (8 groups of 8)
__device__ void stageD(int blk, int d,
        const float* __restrict__ c3r_, const float* __restrict__ c4r_,
        const float* __restrict__ W3w, const float* __restrict__ Ws4) {
    const float* c3 = c3r_ + (size_t)(d%3) * C3SZ;
    const float* s4 = c4r_ + (size_t)((d+1)%2) * C4SZ;
    float* c4 = (float*)c4r_ + (size_t)(d%2) * C4SZ;
    int p = (blk % 7)*256 + threadIdx.x;
    if (p >= N8) return;
    int og = blk / 7;
    int y = p / W8, x = p - y*W8;
    int offsA[9]; float mskA[9];
#pragma unroll
    for (int k = 0; k < 9; k++) {
        int yy = 2*y + k/3, xx = 2*x + k%3;
        bool v = (yy < H4) && (xx < W4);
        offsA[k] = v ? yy*W4 + xx : 0;
        mskA[k] = v ? 1.0f : 0.0f;
    }
    int offsB[9]; float mskB[9];
#pragma unroll
    for (int k = 0; k < 9; k++) {
        int yy = y + k/3 - 1, xx = x + k%3 - 1;
        bool v = (yy >= 0) && (yy < H8) && (xx >= 0) && (xx < W8);
        offsB[k] = v ? yy*W8 + xx : 0;
        mskB[k] = v ? 1.0f : 0.0f;
    }
    float acc[8];
#pragma unroll
    for (int o = 0; o < 8; o++) acc[o] = 0.0f;
#pragma unroll 1
    for (int ci = 0; ci < 32; ci++) {
        const float* b = c3 + ci*N4;
        float t[9];
#pragma unroll
        for (int k = 0; k < 9; k++) t[k] = b[offsA[k]] * mskA[k];
#pragma unroll
        for (int o = 0; o < 8; o++) {
            const float* w = W3w + ((og*8 + o)*32 + ci)*9;
            float a = acc[o];
#pragma unroll
            for (int k = 0; k < 9; k++) a += t[k] * w[k];
            acc[o] = a;
        }
    }
#pragma unroll 1
    for (int ci = 0; ci < 64; ci++) {
        const float* b = s4 + ci*N8;
        float t[9];
#pragma unroll
        for (int k = 0; k < 9; k++) t[k] = b[offsB[k]] * mskB[k];
#pragma unroll
        for (int o = 0; o < 8; o++) {
            const float* w = Ws4 + ((og*8 + o)*64 + ci)*9;
            float a = acc[o];
#pragma unroll
            for (int k = 0; k < 9; k++) a += t[k] * w[k];
            acc[o] = a;
        }
    }
#pragma unroll
    for (int o = 0; o < 8; o++) c4[(og*8 + o)*N8 + p] = fmaxf(acc[o], 0.0f);
}

// U: up4+up3+up2+cost+accumulate. blk in [0,400), band-swizzled.
__device__ void stageU(int blk, int d,
        const float* __restrict__ c1r, const float* __restrict__ c2r_,
        const float* __restrict__ c3r_, const float* __restrict__ c4r_,
        const float* __restrict__ U4, const float* __restrict__ U3,
        const float* __restrict__ U2, const float* __restrict__ Wout,
        const float* __restrict__ depthv,
        float* __restrict__ exp_sum, float* __restrict__ depth_img,
        float* __restrict__ max_prob, float* smem) {
    const float* c1 = c1r + (size_t)(d%5) * C1SZ;
    const float* c2 = c2r_ + (size_t)(d%4) * C2SZ;
    const float* c3 = c3r_ + (size_t)(d%3) * C3SZ;
    const float* c4 = c4r_ + (size_t)(d%2) * C4SZ;
    const float* dslice = depthv + (size_t)d * NP;
    float* u3s = smem;               // [32][36]
    float* u2s = smem + 32*36;       // [16][100]
    float* u1s = smem + 32*36 + 16*100; // [8][NHALO]

    int L = band_tile(blk);
    int bx = L % 20, by = L / 20;
    int ox0 = bx*16, oy0 = by*16;
    int qy0 = (oy0 >> 2) - 1, qx0 = (ox0 >> 2) - 1;
    int hy0 = (oy0 >> 1) - 1, hx0 = (ox0 >> 1) - 1;

#pragma unroll 1
    for (int i = threadIdx.x; i < 32*36; i += 256) {
        int ch = i / 36, pp = i - ch*36;
        int y4 = qy0 + pp/6, x4 = qx0 + pp%6;
        int y4c = min(max(y4, 0), H4-1), x4c = min(max(x4, 0), W4-1);
        int pl = (y4c >> 1)*W8 + (x4c >> 1);
        const float* w = U4 + ch*64;
        float s = c3[ch*N4 + y4c*W4 + x4c];
#pragma unroll 8
        for (int ci = 0; ci < 64; ci++) s += c4[ci*N8 + pl] * w[ci];
        u3s[ch*36 + pp] = s;
    }
    __syncthreads();
#pragma unroll 1
    for (int i = threadIdx.x; i < 16*100; i += 256) {
        int ch = i / 100, pp = i - ch*100;
        int y2 = hy0 + pp/10, x2 = hx0 + pp%10;
        int y2c = min(max(y2, 0), H2-1), x2c = min(max(x2, 0), W2-1);
        int ly = (y2c >> 1) - qy0, lx = (x2c >> 1) - qx0;
        const float* w = U3 + ch*32;
        float s = c2[ch*N2 + y2c*W2 + x2c];
#pragma unroll 8
        for (int ci = 0; ci < 32; ci++) s += u3s[ci*36 + ly*6 + lx] * w[ci];
        u2s[ch*100 + pp] = s;
    }
    __syncthreads();
#pragma unroll 1
    for (int i = threadIdx.x; i < 8*NHALO; i += 256) {
        int ch = i / NHALO, pp = i - ch*NHALO;
        int gy = oy0 + pp/HALO - 1, gx = ox0 + pp%HALO - 1;
        float s = 0.0f;
        if (gy >= 0 && gy < HH && gx >= 0 && gx < WW) {
            int ly = (gy >> 1) - hy0, lx = (gx >> 1) - hx0;
            const float* w = U2 + ch*16;
            s = c1[ch*NP + gy*WW + gx];
#pragma unroll
            for (int ci = 0; ci < 16; ci++) s += u2s[ci*100 + ly*10 + lx] * w[ci];
        }
        u1s[ch*NHALO + pp] = s;
    }
    __syncthreads();
    int px = threadIdx.x & 15, py = threadIdx.x >> 4;
    int base = py*HALO + px;
    float cost = 0.0f;
#pragma unroll 1
    for (int ci = 0; ci < 8; ci++) {
        const float* w = Wout + ci*9;
#pragma unroll
        for (int ky = 0; ky < 3; ky++)
#pragma unroll
            for (int kx = 0; kx < 3; kx++)
                cost += u1s[ci*NHALO + base + ky*HALO + kx] * w[ky*3 + kx];
    }
    int p = (oy0 + py)*WW + ox0 + px;
    float prob = expf(cost);
    exp_sum[p] += prob;
    depth_img[p] += dslice[p] * prob;
    max_prob[p] = fmaxf(max_prob[p], prob);
}

// ================= uber kernel: one diagonal of the pipeline =================
// blocks: A [0,400) B [400,600) C [600,700) D [700,756) U [756,1156)
// launch_bounds(256,6): 6 blocks/CU -> one dispatch generation (1536 >= 1156).
__global__ __launch_bounds__(256, 6) void k_uber(
        int t, int useT,
        const float* __restrict__ feats, const __half* __restrict__ featsT,
        const float* __restrict__ rel,
        const float* __restrict__ depthv,
        const float* __restrict__ W0, const float* __restrict__ Ws1,
        const float* __restrict__ W1, const float* __restrict__ Ws2,
        const float* __restrict__ W2w, const float* __restrict__ Ws3,
        const float* __restrict__ W3w, const float* __restrict__ Ws4,
        const float* __restrict__ U4, const float* __restrict__ U3,
        const float* __restrict__ U2, const float* __restrict__ Wout,
        float* __restrict__ c1r, float* __restrict__ c2r,
        float* __restrict__ c3r, float* __restrict__ c4r,
        float* __restrict__ esum, float* __restrict__ dimg,
        float* __restrict__ maxp) {
    __shared__ float smem[SMEM_FLOATS];
    int b = blockIdx.x;
    if (b < 400) {
        int d = t;
        if (d < DD) stageA(b, d, useT, feats, featsT, rel, depthv, c1r, W0, Ws1, smem);
    } else if (b < 600) {
        int d = t - 1;
        if (d >= 0 && d < DD) stageB(b - 400, d, c1r, c2r, W1, Ws2);
    } else if (b < 700) {
        int d = t - 2;
        if (d >= 0 && d < DD) stageC(b - 600, d, c2r, c3r, W2w, Ws3);
    } else if (b < 756) {
        int d = t - 3;
        if (d >= 0 && d < DD) stageD(b - 700, d, c3r, c4r, W3w, Ws4);
    } else {
        int d = t - 4;
        if (d >= 0 && d < DD)
            stageU(b - 756, d, c1r, c2r, c3r, c4r, U4, U3, U2, Wout, depthv,
                   esum, dimg, maxp, smem);
    }
}

// ---------------- final normalize ----------------
__global__ __launch_bounds__(256) void k_final(
        const float* __restrict__ exp_sum, const float* __restrict__ depth_img,
        const float* __restrict__ max_prob, float* __restrict__ out) {
    int p = blockIdx.x*256 + threadIdx.x;
    if (p >= NP) return;
    float es = exp_sum[p] + 1e-10f;
    out[p] = depth_img[p] / es;
    out[NP + p] = max_prob[p] / es;
}

extern "C" void kernel_launch(void* const* d_in, const int* in_sizes, int n_in,
                              void* d_out, int out_size, void* d_ws, size_t ws_size,
                              hipStream_t stream) {
    const float* feats = (const float*)d_in[0];
    const float* proj  = (const float*)d_in[1];
    const float* depthv= (const float*)d_in[2];
    const float* W0  = (const float*)d_in[3];
    const float* Ws1 = (const float*)d_in[4];
    const float* W1  = (const float*)d_in[5];
    const float* Ws2 = (const float*)d_in[6];
    const float* W2w = (const float*)d_in[7];
    const float* Ws3 = (const float*)d_in[8];
    const float* W3w = (const float*)d_in[9];
    const float* Ws4 = (const float*)d_in[10];
    const float* U4  = (const float*)d_in[11];
    const float* U3  = (const float*)d_in[12];
    const float* U2  = (const float*)d_in[13];
    const float* Wout= (const float*)d_in[14];

    float* ws = (float*)d_ws;
    float* rel  = ws + OFF_REL;
    float* c1r  = ws + OFF_C1R;
    float* c2r  = ws + OFF_C2R;
    float* c3r  = ws + OFF_C3R;
    float* c4r  = ws + OFF_C4R;
    float* esum = ws + OFF_ESUM;
    float* dimg = ws + OFF_DIMG;
    float* maxp = ws + OFF_MAXP;

    // channel-last fp16 feats copy only if the workspace can hold it
    int useT = (ws_size >= (size_t)OFF_END * sizeof(float)) ? 1 : 0;
    __half* featsT = (__half*)(useT ? (ws + OFF_FT) : ws);   // dummy when unused

    // zero all rings + accumulators; ring slots double as the zero "previous
    // skip" inputs for d=0.
    hipMemsetAsync(c1r, 0, (size_t)(OFF_ACCE - OFF_C1R) * sizeof(float), stream);
    k_prep<<<1, 1, 0, stream>>>(proj, rel);
    if (useT)
        k_transpose<<<dim3(3*1600), 256, 0, stream>>>(feats, featsT);

    for (int t = 0; t < DD + 4; t++) {
        k_uber<<<dim3(1156), 256, 0, stream>>>(t, useT, feats, featsT, rel, depthv,
            W0, Ws1, W1, Ws2, W2w, Ws3, W3w, Ws4, U4, U3, U2, Wout,
            c1r, c2r, c3r, c4r, esum, dimg, maxp);
    }
    k_final<<<dim3(400), 256, 0, stream>>>(esum, dimg, maxp, (float*)d_out);
}

// Round 17
// 2577.182 us; speedup vs baseline: 1.4920x; 1.4920x over previous
//
#include <hip/hip_runtime.h>
#include <hip/hip_fp16.h>
#include <math.h>

// Problem constants
#define HH 320
#define WW 320
#define NP (HH*WW)        // 102400
#define CC 32
#define DD 32

#define H2 160
#define W2 160
#define N2 (H2*W2)        // 25600
#define H4 80
#define W4 80
#define N4 (H4*W4)        // 6400
#define H8 40
#define W8 40
#define N8 (H8*W8)        // 1600

#define HALO 18
#define NHALO (HALO*HALO) // 324

// ring strides (floats)
#define C1SZ (8*NP)       // 819200
#define C2SZ (16*N2)      // 409600
#define C3SZ (32*N4)      // 204800
#define C4SZ (64*N8)      // 102400

// stageA [16][NHALO] half2 = 20736 B (s1 [8][NHALO] f32 aliased);
// stageU needs 5344 f32 = 21376 B -> governs allocation.
// 6 blocks/CU x 21376 B = 128 KB < 160 KB LDS: fits.
#define SMEM_FLOATS 5344

// ---------------- workspace layout (float offsets) ----------------
#define OFF_REL   0                        // 24 used, pad 64
#define OFF_C1R   64                       // ring of 5
#define OFF_C2R   (OFF_C1R + 5*C1SZ)       // ring of 4
#define OFF_C3R   (OFF_C2R + 4*C2SZ)       // ring of 3
#define OFF_C4R   (OFF_C3R + 3*C3SZ)       // ring of 2
#define OFF_ESUM  (OFF_C4R + 2*C4SZ)
#define OFF_DIMG  (OFF_ESUM + NP)
#define OFF_MAXP  (OFF_DIMG + NP)
#define OFF_ACCE  (OFF_MAXP + NP)          // end of zero-init region (~27.4 MiB)
// channel-last fp16 copy of feats: [3 views][NP][32 ch] (+19.7 MiB)
#define OFF_FT    OFF_ACCE
#define OFF_END   (OFF_FT + (3*CC*NP)/2)

// ---------------- prep: rel = proj[v] @ inv(proj[0]), v=1,2 ----------------
__global__ void k_prep(const float* __restrict__ proj, float* __restrict__ rel) {
    if (threadIdx.x != 0 || blockIdx.x != 0) return;
    float a[4][4], inv[4][4];
#pragma unroll
    for (int i = 0; i < 4; i++)
#pragma unroll
        for (int j = 0; j < 4; j++) {
            a[i][j] = proj[i*4 + j];
            inv[i][j] = (i == j) ? 1.0f : 0.0f;
        }
#pragma unroll
    for (int c = 0; c < 4; c++) {
        float s = 1.0f / a[c][c];
#pragma unroll
        for (int j = 0; j < 4; j++) { a[c][j] *= s; inv[c][j] *= s; }
#pragma unroll
        for (int r = 0; r < 4; r++) if (r != c) {
            float f = a[r][c];
#pragma unroll
            for (int j = 0; j < 4; j++) {
                a[r][j] -= f * a[c][j];
                inv[r][j] -= f * inv[c][j];
            }
        }
    }
#pragma unroll
    for (int v = 1; v < 3; v++) {
        const float* P = proj + v*16;
        float rm[3][4];
#pragma unroll
        for (int i = 0; i < 3; i++)
#pragma unroll
            for (int j = 0; j < 4; j++) {
                float s = 0.0f;
#pragma unroll
                for (int k = 0; k < 4; k++) s += P[i*4 + k] * inv[k][j];
                rm[i][j] = s;
            }
        float* o = rel + (v-1)*12;
        o[0]=rm[0][0]; o[1]=rm[0][1]; o[2]=rm[0][2];
        o[3]=rm[1][0]; o[4]=rm[1][1]; o[5]=rm[1][2];
        o[6]=rm[2][0]; o[7]=rm[2][1]; o[8]=rm[2][2];
        o[9]=rm[0][3]; o[10]=rm[1][3]; o[11]=rm[2][3];
    }
}

// ---------------- CHW f32 -> HWC fp16 transpose of all 3 views ------------
__global__ __launch_bounds__(256) void k_transpose(const float* __restrict__ feats,
                                                   __half* __restrict__ featsT) {
    __shared__ float lds[32][65];   // +1 pad
    int g = blockIdx.x;
    int v = g / 1600;
    int p0 = (g - v*1600) * 64;
    const float* src = feats + (size_t)v*CC*NP + p0;
    for (int i = threadIdx.x; i < 32*64; i += 256) {
        int c = i >> 6, pp = i & 63;
        lds[c][pp] = src[(size_t)c*NP + pp];       // coalesced reads
    }
    __syncthreads();
    __half* dst = featsT + ((size_t)v*NP + p0)*32;
    int pp = threadIdx.x >> 2, cq = (threadIdx.x & 3) * 8;
    __half2 h[4];
#pragma unroll
    for (int j = 0; j < 4; j++)
        h[j] = __floats2half2_rn(lds[cq+2*j][pp], lds[cq+2*j+1][pp]);
    *(float4*)(dst + (size_t)pp*32 + cq) = *(float4*)h;   // 16B coalesced store
}

// ---- fp16 8-channel (16 B) helpers ----
__device__ __forceinline__ void set_hline8(const __half* base, float* s) {
    float4 raw = *(const float4*)base;
    const __half2* h2 = (const __half2*)&raw;
#pragma unroll
    for (int j = 0; j < 4; j++) {
        float2 f = __half22float2(h2[j]);
        s[2*j]     = f.x;
        s[2*j + 1] = f.y;
    }
}
__device__ __forceinline__ void acc_hline8(const __half* base, float w, float* t) {
    float4 raw = *(const float4*)base;
    const __half2* h2 = (const __half2*)&raw;
#pragma unroll
    for (int j = 0; j < 4; j++) {
        float2 f = __half22float2(h2[j]);
        t[2*j]     += f.x * w;
        t[2*j + 1] += f.y * w;
    }
}

// XCD band swizzle (round-robin block->XCD).
__device__ __forceinline__ int band_tile(int blk) { return (blk & 7) * 50 + (blk >> 3); } // [0,400)

// ================= stage device functions =================
// Allocator note (rounds 13-16): launch_bounds(256,N) drives a hard VGPR
// target of ~256/N; anything live beyond it spills to scratch. At N=6 the
// cap is 40, so stageA keeps its live set ~32 regs: NO offset/weight arrays
// live across loops — projection is recomputed per quarter per view and
// taps are consumed as scalar temps.

// A: warp+variance+conv1, 16x16 tile; blk in [0,400) band-swizzled.
__device__ void stageA(int blk, int d, int useT,
        const float* __restrict__ feats, const __half* __restrict__ featsT,
        const float* __restrict__ rel,
        const float* __restrict__ depthv, const float* __restrict__ c1r,
        const float* __restrict__ W0, const float* __restrict__ Ws1,
        float* smem) {
    __half2* pbuf = (__half2*)smem;       // [16 ch-pairs][NHALO]
    float* fbuf = smem;                   // [8][NHALO] for the s1 phase
    const float* dslice = depthv + (size_t)d * NP;
    const float* s1 = c1r + (size_t)((d+4)%5) * C1SZ;   // c1_{d-1} (zeros for d=0)
    float* c1out = (float*)c1r + (size_t)(d%5) * C1SZ;

    int L = band_tile(blk);
    int bx = L % 20, by = L / 20;
    int ox0 = bx*16, oy0 = by*16;

    const float inv3 = 1.0f / 3.0f;

    int opx = threadIdx.x & 15, opy = threadIdx.x >> 4;
    int obase = opy*HALO + opx;
    int outp = (oy0 + opy)*WW + ox0 + opx;

    // ---- variance pass: <=2 halo pixels / thread, 4 channel-quarters ----
#pragma unroll 1
    for (int s = 0; s < 2; s++) {
        int hp = threadIdx.x + s*256;
        if (hp >= NHALO) break;
        int hy = hp / HALO, hx = hp - hy*HALO;
        int gy = oy0 + hy - 1, gx = ox0 + hx - 1;
        if (gy < 0 || gy >= HH || gx < 0 || gx >= WW) {
            __half2 z = __floats2half2_rn(0.0f, 0.0f);
#pragma unroll 1
            for (int c = 0; c < 16; c++) pbuf[c*NHALO + hp] = z;
            continue;
        }
        int p = gy*WW + gx;
        float depth = dslice[p];
        float fx = (float)gx, fy = (float)gy;

#pragma unroll 1
        for (int q = 0; q < 4; q++) {
            int cb = q * 8;
            float sum[8], sq[8];
            if (useT) {
                set_hline8(featsT + ((size_t)p << 5) + cb, sum);
#pragma unroll
                for (int c = 0; c < 8; c++) sq[c] = sum[c]*sum[c];
#pragma unroll
                for (int v = 0; v < 2; v++) {
                    // projection recomputed per quarter: no arrays live
                    const float* r = rel + v*12;
                    float X = (r[0]*fx + r[1]*fy + r[2]) * depth + r[9];
                    float Y = (r[3]*fx + r[4]*fy + r[5]) * depth + r[10];
                    float Z = (r[6]*fx + r[7]*fy + r[8]) * depth + r[11];
                    float iz = 1.0f / Z;
                    float px = X * iz, py = Y * iz;
                    float x0f = floorf(px), y0f = floorf(py);
                    float wx = px - x0f, wy = py - y0f;
                    int x0 = (int)x0f, y0 = (int)y0f;
                    const __half* fv = featsT + (size_t)(v+1)*CC*NP;
                    float t[8];
#pragma unroll
                    for (int c = 0; c < 8; c++) t[c] = 0.0f;
#pragma unroll
                    for (int tp = 0; tp < 4; tp++) {
                        int xi = x0 + (tp & 1), yi = y0 + (tp >> 1);
                        float wgt = ((tp & 1) ? wx : 1.0f - wx)
                                  * ((tp >> 1) ? wy : 1.0f - wy);
                        bool valid = (xi >= 0) && (xi <= WW-1) &&
                                     (yi >= 0) && (yi <= HH-1);
                        int xc = min(max(xi, 0), WW-1);
                        int yc = min(max(yi, 0), HH-1);
                        acc_hline8(fv + ((size_t)(yc*WW + xc) << 5) + cb,
                                   valid ? wgt : 0.0f, t);
                    }
#pragma unroll
                    for (int c = 0; c < 8; c++) { sum[c] += t[c]; sq[c] += t[c]*t[c]; }
                }
            } else {
                // fallback: scalar CHW gathers; per-view inline offsets
#pragma unroll
                for (int c = 0; c < 8; c++) {
                    float rv = feats[(cb+c)*NP + p];
                    sum[c] = rv; sq[c] = rv*rv;
                }
#pragma unroll
                for (int v = 0; v < 2; v++) {
                    const float* r = rel + v*12;
                    float X = (r[0]*fx + r[1]*fy + r[2]) * depth + r[9];
                    float Y = (r[3]*fx + r[4]*fy + r[5]) * depth + r[10];
                    float Z = (r[6]*fx + r[7]*fy + r[8]) * depth + r[11];
                    float iz = 1.0f / Z;
                    float px = X * iz, py = Y * iz;
                    float x0f = floorf(px), y0f = floorf(py);
                    float wx = px - x0f, wy = py - y0f;
                    int x0 = (int)x0f, y0 = (int)y0f;
                    bool vax = (x0 >= 0) && (x0 < WW), vbx = (x0 >= -1) && (x0 < WW-1);
                    bool vay = (y0 >= 0) && (y0 < HH), vby = (y0 >= -1) && (y0 < HH-1);
                    int xa = min(max(x0, 0), WW-1), xb = min(max(x0+1, 0), WW-1);
                    int ya = min(max(y0, 0), HH-1), yb = min(max(y0+1, 0), HH-1);
                    int o0 = ya*WW + xa, o1 = ya*WW + xb;
                    int o2 = yb*WW + xa, o3 = yb*WW + xb;
                    float w0 = (vax && vay) ? (1.0f-wx)*(1.0f-wy) : 0.0f;
                    float w1 = (vbx && vay) ? wx*(1.0f-wy) : 0.0f;
                    float w2 = (vax && vby) ? (1.0f-wx)*wy : 0.0f;
                    float w3 = (vbx && vby) ? wx*wy : 0.0f;
                    const float* fb = feats + (size_t)(v+1)*CC*NP;
#pragma unroll 1
                    for (int c = 0; c < 8; c++) {
                        const float* b = fb + (cb+c)*NP;
                        float tv = b[o0]*w0 + b[o1]*w1 + b[o2]*w2 + b[o3]*w3;
                        sum[c] += tv; sq[c] += tv*tv;
                    }
                }
            }
#pragma unroll
            for (int c = 0; c < 4; c++) {
                float m0 = sum[2*c] * inv3,   v0 = sq[2*c] * inv3 - m0*m0;
                float m1 = sum[2*c+1] * inv3, v1 = sq[2*c+1] * inv3 - m1*m1;
                pbuf[(q*4 + c)*NHALO + hp] = __floats2half2_rn(v0, v1);
            }
        }
    }
    __syncthreads();

    float acc[8];
#pragma unroll
    for (int o = 0; o < 8; o++) acc[o] = 0.0f;

#pragma unroll 1
    for (int cp = 0; cp < 16; cp++) {
        float t0[9], t1[9];
#pragma unroll
        for (int ky = 0; ky < 3; ky++)
#pragma unroll
            for (int kx = 0; kx < 3; kx++) {
                __half2 h = pbuf[cp*NHALO + obase + ky*HALO + kx];
                t0[ky*3+kx] = __low2float(h);
                t1[ky*3+kx] = __high2float(h);
            }
#pragma unroll
        for (int o = 0; o < 8; o++) {
            const float* w0 = W0 + (o*32 + 2*cp)*9;
            float a = acc[o];
#pragma unroll
            for (int k = 0; k < 9; k++) a += t0[k] * w0[k];
#pragma unroll
            for (int k = 0; k < 9; k++) a += t1[k] * w0[9 + k];
            acc[o] = a;
        }
    }
    __syncthreads();   // before s1 staging overwrites buf

    // s1 chunk (8 channels, f32 in LDS)
#pragma unroll 1
    for (int hp = threadIdx.x; hp < NHALO; hp += 256) {
        int hy = hp / HALO, hx = hp - hy*HALO;
        int gy = oy0 + hy - 1, gx = ox0 + hx - 1;
        bool v = (gy >= 0) && (gy < HH) && (gx >= 0) && (gx < WW);
        int p = v ? gy*WW + gx : 0;
#pragma unroll
        for (int c = 0; c < 8; c++) fbuf[c*NHALO + hp] = v ? s1[c*NP + p] : 0.0f;
    }
    __syncthreads();
#pragma unroll 1
    for (int ci = 0; ci < 8; ci++) {
        float t[9];
#pragma unroll
        for (int ky = 0; ky < 3; ky++)
#pragma unroll
            for (int kx = 0; kx < 3; kx++) t[ky*3+kx] = fbuf[ci*NHALO + obase + ky*HALO + kx];
#pragma unroll
        for (int o = 0; o < 8; o++) {
            const float* w = Ws1 + (o*8 + ci)*9;
            float a = acc[o];
#pragma unroll
            for (int k = 0; k < 9; k++) a += t[k] * w[k];
            acc[o] = a;
        }
    }
#pragma unroll
    for (int o = 0; o < 8; o++) c1out[o*NP + outp] = fmaxf(acc[o], 0.0f);
}

// B: conv2. blk in [0,200): px_chunk = blk%100, og = blk/100 (2 groups of 8)
__device__ void stageB(int blk, int d,
        const float* __restrict__ c1r, const float* __restrict__ c2r_,
        const float* __restrict__ W1, const float* __restrict__ Ws2) {
    const float* c1 = c1r + (size_t)(d%5) * C1SZ;
    const float* s2 = c2r_ + (size_t)((d+3)%4) * C2SZ;
    float* c2 = (float*)c2r_ + (size_t)(d%4) * C2SZ;
    int p = (blk % 100)*256 + threadIdx.x;
    int og = blk / 100;
    int y = p / W2, x = p - y*W2;
    int offsA[9]; float mskA[9];
#pragma unroll
    for (int k = 0; k < 9; k++) {
        int yy = 2*y + k/3, xx = 2*x + k%3;
        bool v = (yy < HH) && (xx < WW);
        offsA[k] = v ? yy*WW + xx : 0;
        mskA[k] = v ? 1.0f : 0.0f;
    }
    int offsB[9]; float mskB[9];
#pragma unroll
    for (int k = 0; k < 9; k++) {
        int yy = y + k/3 - 1, xx = x + k%3 - 1;
        bool v = (yy >= 0) && (yy < H2) && (xx >= 0) && (xx < W2);
        offsB[k] = v ? yy*W2 + xx : 0;
        mskB[k] = v ? 1.0f : 0.0f;
    }
    float acc[8];
#pragma unroll
    for (int o = 0; o < 8; o++) acc[o] = 0.0f;
#pragma unroll 1
    for (int ci = 0; ci < 8; ci++) {
        const float* b = c1 + ci*NP;
        float t[9];
#pragma unroll
        for (int k = 0; k < 9; k++) t[k] = b[offsA[k]] * mskA[k];
#pragma unroll
        for (int o = 0; o < 8; o++) {
            const float* w = W1 + ((og*8 + o)*8 + ci)*9;
            float a = acc[o];
#pragma unroll
            for (int k = 0; k < 9; k++) a += t[k] * w[k];
            acc[o] = a;
        }
    }
#pragma unroll 1
    for (int ci = 0; ci < 16; ci++) {
        const float* b = s2 + ci*N2;
        float t[9];
#pragma unroll
        for (int k = 0; k < 9; k++) t[k] = b[offsB[k]] * mskB[k];
#pragma unroll
        for (int o = 0; o < 8; o++) {
            const float* w = Ws2 + ((og*8 + o)*16 + ci)*9;
            float a = acc[o];
#pragma unroll
            for (int k = 0; k < 9; k++) a += t[k] * w[k];
            acc[o] = a;
        }
    }
#pragma unroll
    for (int o = 0; o < 8; o++) c2[(og*8 + o)*N2 + p] = fmaxf(acc[o], 0.0f);
}

// C: conv3. blk in [0,100): px_chunk = blk%25, og = blk/25 (4 groups of 8)
__device__ void stageC(int blk, int d,
        const float* __restrict__ c2r_, const float* __restrict__ c3r_,
        const float* __restrict__ W2w, const float* __restrict__ Ws3) {
    const float* c2 = c2r_ + (size_t)(d%4) * C2SZ;
    const float* s3 = c3r_ + (size_t)((d+2)%3) * C3SZ;
    float* c3 = (float*)c3r_ + (size_t)(d%3) * C3SZ;
    int p = (blk % 25)*256 + threadIdx.x;
    int og = blk / 25;
    int y = p / W4, x = p - y*W4;
    int offsA[9]; float mskA[9];
#pragma unroll
    for (int k = 0; k < 9; k++) {
        int yy = 2*y + k/3, xx = 2*x + k%3;
        bool v = (yy < H2) && (xx < W2);
        offsA[k] = v ? yy*W2 + xx : 0;
        mskA[k] = v ? 1.0f : 0.0f;
    }
    int offsB[9]; float mskB[9];
#pragma unroll
    for (int k = 0; k < 9; k++) {
        int yy = y + k/3 - 1, xx = x + k%3 - 1;
        bool v = (yy >= 0) && (yy < H4) && (xx >= 0) && (xx < W4);
        offsB[k] = v ? yy*W4 + xx : 0;
        mskB[k] = v ? 1.0f : 0.0f;
    }
    float acc[8];
#pragma unroll
    for (int o = 0; o < 8; o++) acc[o] = 0.0f;
#pragma unroll 1
    for (int ci = 0; ci < 16; ci++) {
        const float* b = c2 + ci*N2;
        float t[9];
#pragma unroll
        for (int k = 0; k < 9; k++) t[k] = b[offsA[k]] * mskA[k];
#pragma unroll
        for (int o = 0; o < 8; o++) {
            const float* w = W2w + ((og*8 + o)*16 + ci)*9;
            float a = acc[o];
#pragma unroll
            for (int k = 0; k < 9; k++) a += t[k] * w[k];
            acc[o] = a;
        }
    }
#pragma unroll 1
    for (int ci = 0; ci < 32; ci++) {
        const float* b = s3 + ci*N4;
        float t[9];
#pragma unroll
        for (int k = 0; k < 9; k++) t[k] = b[offsB[k]] * mskB[k];
#pragma unroll
        for (int o = 0; o < 8; o++) {
            const float* w = Ws3 + ((og*8 + o)*32 + ci)*9;
            float a = acc[o];
#pragma unroll
            for (int k = 0; k < 9; k++) a += t[k] * w[k];
            acc[o] = a;
        }
    }
#pragma unroll
    for (int o = 0; o < 8; o++) c3[(og*8 + o)*N4 + p] = fmaxf(acc[o], 0.0f);
}

// D: conv4. blk in [0,56): px_chunk = blk%7, og = blk/7 (8 groups of 8)
__device__ void stageD(int blk, int d,
        const float* __restrict__ c3r_, const float* __restrict__ c4r_,
        const float* __restrict__ W3w, const float* __restrict__ Ws4) {
    const float* c3 = c3r_ + (size_t)(d%3) * C3SZ;
    const float* s4 = c4r_ + (size_t)((d+1)%2) * C4SZ;
    float* c4 = (float*)c4r_ + (size_t)(d%2) * C4SZ;
    int p = (blk % 7)*256 + threadIdx.x;
    if (p >= N8) return;
    int og = blk / 7;
    int y = p / W8, x = p - y*W8;
    int offsA[9]; float mskA[9];
#pragma unroll
    for (int k = 0; k < 9; k++) {
        int yy = 2*y + k/3, xx = 2*x + k%3;
        bool v = (yy < H4) && (xx < W4);
        offsA[k] = v ? yy*W4 + xx : 0;
        mskA[k] = v ? 1.0f : 0.0f;
    }
    int offsB[9]; float mskB[9];
#pragma unroll
    for (int k = 0; k < 9; k++) {
        int yy = y + k/3 - 1, xx = x + k%3 - 1;
        bool v = (yy >= 0) && (yy < H8) && (xx >= 0) && (xx < W8);
        offsB[k] = v ? yy*W8 + xx : 0;
        mskB[k] = v ? 1.0f : 0.0f;
    }
    float acc[8];
#pragma unroll
    for (int o = 0; o < 8; o++) acc[o] = 0.0f;
#pragma unroll 1
    for (int ci = 0; ci < 32; ci++) {
        const float* b = c3 + ci*N4;
        float t[9];
#pragma unroll
        for (int k = 0; k < 9; k++) t[k] = b[offsA[k]] * mskA[k];
#pragma unroll
        for (int o = 0; o < 8; o++) {
            const float* w = W3w + ((og*8 + o)*32 + ci)*9;
            float a = acc[o];
#pragma unroll
            for (int k = 0; k < 9; k++) a += t[k] * w[k];
            acc[o] = a;
        }
    }
#pragma unroll 1
    for (int ci = 0; ci < 64; ci++) {
        const float* b = s4 + ci*N8;
        float t[9];
#pragma unroll
        for (int k = 0; k < 9; k++) t[k] = b[offsB[k]] * mskB[k];
#pragma unroll
        for (int o = 0; o < 8; o++) {
            const float* w = Ws4 + ((og*8 + o)*64 + ci)*9;
            float a = acc[o];
#pragma unroll
            for (int k = 0; k < 9; k++) a += t[k] * w[k];
            acc[o] = a;
        }
    }
#pragma unroll
    for (int o = 0; o < 8; o++) c4[(og*8 + o)*N8 + p] = fmaxf(acc[o], 0.0f);
}

// U: up4+up3+up2+cost+accumulate. blk in [0,400), band-swizzled.
__device__ void stageU(int blk, int d,
        const float* __restrict__ c1r, const float* __restrict__ c2r_,
        const float* __restrict__ c3r_, const float* __restrict__ c4r_,
        const float* __restrict__ U4, const float* __restrict__ U3,
        const float* __restrict__ U2, const float* __restrict__ Wout,
        const float* __restrict__ depthv,
        float* __restrict__ exp_sum, float* __restrict__ depth_img,
        float* __restrict__ max_prob, float* smem) {
    const float* c1 = c1r + (size_t)(d%5) * C1SZ;
    const float* c2 = c2r_ + (size_t)(d%4) * C2SZ;
    const float* c3 = c3r_ + (size_t)(d%3) * C3SZ;
    const float* c4 = c4r_ + (size_t)(d%2) * C4SZ;
    const float* dslice = depthv + (size_t)d * NP;
    float* u3s = smem;               // [32][36]
    float* u2s = smem + 32*36;       // [16][100]
    float* u1s = smem + 32*36 + 16*100; // [8][NHALO]

    int L = band_tile(blk);
    int bx = L % 20, by = L / 20;
    int ox0 = bx*16, oy0 = by*16;
    int qy0 = (oy0 >> 2) - 1, qx0 = (ox0 >> 2) - 1;
    int hy0 = (oy0 >> 1) - 1, hx0 = (ox0 >> 1) - 1;

#pragma unroll 1
    for (int i = threadIdx.x; i < 32*36; i += 256) {
        int ch = i / 36, pp = i - ch*36;
        int y4 = qy0 + pp/6, x4 = qx0 + pp%6;
        int y4c = min(max(y4, 0), H4-1), x4c = min(max(x4, 0), W4-1);
        int pl = (y4c >> 1)*W8 + (x4c >> 1);
        const float* w = U4 + ch*64;
        float s = c3[ch*N4 + y4c*W4 + x4c];
#pragma unroll 8
        for (int ci = 0; ci < 64; ci++) s += c4[ci*N8 + pl] * w[ci];
        u3s[ch*36 + pp] = s;
    }
    __syncthreads();
#pragma unroll 1
    for (int i = threadIdx.x; i < 16*100; i += 256) {
        int ch = i / 100, pp = i - ch*100;
        int y2 = hy0 + pp/10, x2 = hx0 + pp%10;
        int y2c = min(max(y2, 0), H2-1), x2c = min(max(x2, 0), W2-1);
        int ly = (y2c >> 1) - qy0, lx = (x2c >> 1) - qx0;
        const float* w = U3 + ch*32;
        float s = c2[ch*N2 + y2c*W2 + x2c];
#pragma unroll 8
        for (int ci = 0; ci < 32; ci++) s += u3s[ci*36 + ly*6 + lx] * w[ci];
        u2s[ch*100 + pp] = s;
    }
    __syncthreads();
#pragma unroll 1
    for (int i = threadIdx.x; i < 8*NHALO; i += 256) {
        int ch = i / NHALO, pp = i - ch*NHALO;
        int gy = oy0 + pp/HALO - 1, gx = ox0 + pp%HALO - 1;
        float s = 0.0f;
        if (gy >= 0 && gy < HH && gx >= 0 && gx < WW) {
            int ly = (gy >> 1) - hy0, lx = (gx >> 1) - hx0;
            const float* w = U2 + ch*16;
            s = c1[ch*NP + gy*WW + gx];
#pragma unroll
            for (int ci = 0; ci < 16; ci++) s += u2s[ci*100 + ly*10 + lx] * w[ci];
        }
        u1s[ch*NHALO + pp] = s;
    }
    __syncthreads();
    int px = threadIdx.x & 15, py = threadIdx.x >> 4;
    int base = py*HALO + px;
    float cost = 0.0f;
#pragma unroll 1
    for (int ci = 0; ci < 8; ci++) {
        const float* w = Wout + ci*9;
#pragma unroll
        for (int ky = 0; ky < 3; ky++)
#pragma unroll
            for (int kx = 0; kx < 3; kx++)
                cost += u1s[ci*NHALO + base + ky*HALO + kx] * w[ky*3 + kx];
    }
    int p = (oy0 + py)*WW + ox0 + px;
    float prob = expf(cost);
    exp_sum[p] += prob;
    depth_img[p] += dslice[p] * prob;
    max_prob[p] = fmaxf(max_prob[p], prob);
}

// ================= uber kernel: one diagonal of the pipeline =================
// blocks: A [0,400) B [400,600) C [600,700) D [700,756) U [756,1156)
// launch_bounds(256,6): 6 blocks/CU -> one dispatch generation (1536 >= 1156).
__global__ __launch_bounds__(256, 6) void k_uber(
        int t, int useT,
        const float* __restrict__ feats, const __half* __restrict__ featsT,
        const float* __restrict__ rel,
        const float* __restrict__ depthv,
        const float* __restrict__ W0, const float* __restrict__ Ws1,
        const float* __restrict__ W1, const float* __restrict__ Ws2,
        const float* __restrict__ W2w, const float* __restrict__ Ws3,
        const float* __restrict__ W3w, const float* __restrict__ Ws4,
        const float* __restrict__ U4, const float* __restrict__ U3,
        const float* __restrict__ U2, const float* __restrict__ Wout,
        float* __restrict__ c1r, float* __restrict__ c2r,
        float* __restrict__ c3r, float* __restrict__ c4r,
        float* __restrict__ esum, float* __restrict__ dimg,
        float* __restrict__ maxp) {
    __shared__ float smem[SMEM_FLOATS];
    int b = blockIdx.x;
    if (b < 400) {
        int d = t;
        if (d < DD) stageA(b, d, useT, feats, featsT, rel, depthv, c1r, W0, Ws1, smem);
    } else if (b < 600) {
        int d = t - 1;
        if (d >= 0 && d < DD) stageB(b - 400, d, c1r, c2r, W1, Ws2);
    } else if (b < 700) {
        int d = t - 2;
        if (d >= 0 && d < DD) stageC(b - 600, d, c2r, c3r, W2w, Ws3);
    } else if (b < 756) {
        int d = t - 3;
        if (d >= 0 && d < DD) stageD(b - 700, d, c3r, c4r, W3w, Ws4);
    } else {
        int d = t - 4;
        if (d >= 0 && d < DD)
            stageU(b - 756, d, c1r, c2r, c3r, c4r, U4, U3, U2, Wout, depthv,
                   esum, dimg, maxp, smem);
    }
}

// ---------------- final normalize ----------------
__global__ __launch_bounds__(256) void k_final(
        const float* __restrict__ exp_sum, const float* __restrict__ depth_img,
        const float* __restrict__ max_prob, float* __restrict__ out) {
    int p = blockIdx.x*256 + threadIdx.x;
    if (p >= NP) return;
    float es = exp_sum[p] + 1e-10f;
    out[p] = depth_img[p] / es;
    out[NP + p] = max_prob[p] / es;
}

extern "C" void kernel_launch(void* const* d_in, const int* in_sizes, int n_in,
                              void* d_out, int out_size, void* d_ws, size_t ws_size,
                              hipStream_t stream) {
    const float* feats = (const float*)d_in[0];
    const float* proj  = (const float*)d_in[1];
    const float* depthv= (const float*)d_in[2];
    const float* W0  = (const float*)d_in[3];
    const float* Ws1 = (const float*)d_in[4];
    const float* W1  = (const float*)d_in[5];
    const float* Ws2 = (const float*)d_in[6];
    const float* W2w = (const float*)d_in[7];
    const float* Ws3 = (const float*)d_in[8];
    const float* W3w = (const float*)d_in[9];
    const float* Ws4 = (const float*)d_in[10];
    const float* U4  = (const float*)d_in[11];
    const float* U3  = (const float*)d_in[12];
    const float* U2  = (const float*)d_in[13];
    const float* Wout= (const float*)d_in[14];

    float* ws = (float*)d_ws;
    float* rel  = ws + OFF_REL;
    float* c1r  = ws + OFF_C1R;
    float* c2r  = ws + OFF_C2R;
    float* c3r  = ws + OFF_C3R;
    float* c4r  = ws + OFF_C4R;
    float* esum = ws + OFF_ESUM;
    float* dimg = ws + OFF_DIMG;
    float* maxp = ws + OFF_MAXP;

    // channel-last fp16 feats copy only if the workspace can hold it
    int useT = (ws_size >= (size_t)OFF_END * sizeof(float)) ? 1 : 0;
    __half* featsT = (__half*)(useT ? (ws + OFF_FT) : ws);   // dummy when unused

    // zero all rings + accumulators; ring slots double as the zero "previous
    // skip" inputs for d=0.
    hipMemsetAsync(c1r, 0, (size_t)(OFF_ACCE - OFF_C1R) * sizeof(float), stream);
    k_prep<<<1, 1, 0, stream>>>(proj, rel);
    if (useT)
        k_transpose<<<dim3(3*1600), 256, 0, stream>>>(feats, featsT);

    for (int t = 0; t < DD + 4; t++) {
        k_uber<<<dim3(1156), 256, 0, stream>>>(t, useT, feats, featsT, rel, depthv,
            W0, Ws1, W1, Ws2, W2w, Ws3, W3w, Ws4, U4, U3, U2, Wout,
            c1r, c2r, c3r, c4r, esum, dimg, maxp);
    }
    k_final<<<dim3(400), 256, 0, stream>>>(esum, dimg, maxp, (float*)d_out);
}